// Round 2
// baseline (10170.407 us; speedup 1.0000x reference)
//
#include <hip/hip_runtime.h>
#include <hip/hip_bf16.h>

// Problem constants
constexpr int Bn  = 8;
constexpr int Cn  = 192;   // hidden channels
constexpr int Tn  = 1024;  // sequence length
constexpr int Hn  = 2;     // heads
constexpr int DKn = 96;    // head dim
constexpr int FCn = 768;   // filter channels
constexpr int Ln  = 6;     // layers
constexpr int WINn = 4;    // rel-attn window

// ---------------------------------------------------------------------------
// X = x * mask   (all fp32)
__global__ void cvt_in(const float* __restrict__ x, const float* __restrict__ mask,
                       float* __restrict__ X) {
    int i = blockIdx.x * 256 + threadIdx.x;           // i < B*C*T
    int t = i & (Tn - 1);
    int b = i / (Cn * Tn);
    X[i] = x[i] * mask[b * Tn + t];
}

// out = X * mask
__global__ void cvt_out(const float* __restrict__ X, const float* __restrict__ mask,
                        float* __restrict__ out) {
    int i = blockIdx.x * 256 + threadIdx.x;
    int t = i & (Tn - 1);
    int b = i / (Cn * Tn);
    out[i] = X[i] * mask[b * Tn + t];
}

// ---------------------------------------------------------------------------
// Generic conv1d (cross-correlation, 'same' padding (KS/2, KS/2)) / 1x1 GEMM.
// Y[b,f,t] = act( sum_{c,k} X[b,c,t+k-KS/2] * W[l,f,c,k] + bias[l,f] )
// Tile: 64 (f) x 64 (t) per 256-thread block; K-chunks of 16 channels.
template <int KS>
__global__ __launch_bounds__(256) void conv_k(
        const float* __restrict__ Xin, const float* __restrict__ Wg,
        const float* __restrict__ Bg, float* __restrict__ Yout,
        int CIN, int COUT, int layer, int relu) {
    constexpr int WD = 64 + KS - 1;       // staged x width
    constexpr int RW = 16 * KS + 1;       // ws row stride (+1 anti-bank-conflict)
    __shared__ float xs[16][WD];
    __shared__ float ws[64][RW];

    const int tid = threadIdx.x;
    const int b  = blockIdx.z;
    const int f0 = blockIdx.y * 64;
    const int t0 = blockIdx.x * 64;
    const int tx = tid & 15, ty = tid >> 4;

    const float* Wl = Wg + (size_t)layer * COUT * CIN * KS;

    float acc[4][4] = {};

    for (int c0 = 0; c0 < CIN; c0 += 16) {
        __syncthreads();
        // stage X chunk (16 channels x WD positions), zero-padded at seq edges
        for (int idx = tid; idx < 16 * WD; idx += 256) {
            int r = idx / WD, col = idx % WD;
            int gt = t0 + col - (KS / 2);
            float v = 0.f;
            if (gt >= 0 && gt < Tn) v = Xin[((b * CIN + c0 + r) * Tn) + gt];
            xs[r][col] = v;
        }
        // stage W chunk (64 f x 16 c x KS), contiguous (c,k) in memory
        for (int idx = tid; idx < 64 * 16 * KS; idx += 256) {
            int f = idx / (16 * KS), r = idx % (16 * KS);
            ws[f][r] = Wl[(size_t)(f0 + f) * CIN * KS + (size_t)c0 * KS + r];
        }
        __syncthreads();
#pragma unroll
        for (int cc = 0; cc < 16; ++cc) {
#pragma unroll
            for (int k = 0; k < KS; ++k) {
                float wv[4], xv[4];
#pragma unroll
                for (int i = 0; i < 4; ++i) wv[i] = ws[ty + 16 * i][cc * KS + k];
#pragma unroll
                for (int j = 0; j < 4; ++j) xv[j] = xs[cc][tx + 16 * j + k];
#pragma unroll
                for (int i = 0; i < 4; ++i)
#pragma unroll
                    for (int j = 0; j < 4; ++j) acc[i][j] += wv[i] * xv[j];
            }
        }
    }
#pragma unroll
    for (int i = 0; i < 4; ++i) {
        int f = f0 + ty + 16 * i;
        float bias = Bg[layer * COUT + f];
#pragma unroll
        for (int j = 0; j < 4; ++j) {
            float v = acc[i][j] + bias;
            if (relu) v = fmaxf(v, 0.f);
            Yout[((b * COUT + f) * Tn) + t0 + tx + 16 * j] = v;
        }
    }
}

// ---------------------------------------------------------------------------
// Fused relative-position attention, one block per (b,h,t) query row.
// Q/K/V in [B,C,T] fp32 layout (C = h*DK + d). Writes A in [B,C,T].
__global__ __launch_bounds__(128) void attn_k(
        const float* __restrict__ Q, const float* __restrict__ Kt,
        const float* __restrict__ Vt, const float* __restrict__ mask,
        const float* __restrict__ erk, const float* __restrict__ erv,
        float* __restrict__ A, int layer) {
    __shared__ float qs[DKn];
    __shared__ float sc[Tn];
    __shared__ float red[128];

    const int tid = threadIdx.x;
    const int t = blockIdx.x, h = blockIdx.y, b = blockIdx.z;
    const float scale = 0.10206207261596575f;  // 1/sqrt(96)

    for (int d = tid; d < DKn; d += 128)
        qs[d] = Q[((b * Cn + h * DKn + d) * Tn) + t] * scale;
    __syncthreads();

    // scores: each thread owns s = tid + 128*j
    float acc[8] = {};
    const float* Kb2 = Kt + (size_t)(b * Cn + h * DKn) * Tn;
    for (int d = 0; d < DKn; ++d) {
        float qd = qs[d];
        const float* kr = Kb2 + (size_t)d * Tn;
#pragma unroll
        for (int j = 0; j < 8; ++j) acc[j] += qd * kr[tid + 128 * j];
    }
    const float rowm = mask[b * Tn + t];
    float mx = -3.0e38f;
#pragma unroll
    for (int j = 0; j < 8; ++j) {
        int s = tid + 128 * j;
        int delta = s - t;
        if (delta >= -WINn && delta <= WINn) {  // windowed rel-K bias
            const float* e = erk + ((size_t)layer * (2 * WINn + 1) + (delta + WINn)) * DKn;
            float a = 0.f;
            for (int d = 0; d < DKn; ++d) a += qs[d] * e[d];
            acc[j] += a;
        }
        float mv = mask[b * Tn + s] * rowm;
        float v = (mv != 0.f) ? acc[j] : -1e4f;
        sc[s] = v;
        mx = fmaxf(mx, v);
    }
    // block-wide max
    red[tid] = mx;
    __syncthreads();
    for (int off = 64; off > 0; off >>= 1) {
        if (tid < off) red[tid] = fmaxf(red[tid], red[tid + off]);
        __syncthreads();
    }
    mx = red[0];
    __syncthreads();
    // exp + block-wide sum
    float ls = 0.f;
#pragma unroll
    for (int j = 0; j < 8; ++j) {
        int s = tid + 128 * j;
        float e = __expf(sc[s] - mx);
        sc[s] = e;
        ls += e;
    }
    red[tid] = ls;
    __syncthreads();
    for (int off = 64; off > 0; off >>= 1) {
        if (tid < off) red[tid] += red[tid + off];
        __syncthreads();
    }
    const float inv = 1.f / red[0];

    // out[d] = (sum_s p[s]*V[s,d] + windowed rel-V) / sum
    if (tid < DKn) {
        const int d = tid;
        const float* vr = Vt + (size_t)(b * Cn + h * DKn + d) * Tn;
        float a = 0.f;
#pragma unroll 8
        for (int s = 0; s < Tn; ++s) a += sc[s] * vr[s];
        float ar = 0.f;
        int lo = (t - WINn > 0) ? t - WINn : 0;
        int hi = (t + WINn < Tn - 1) ? t + WINn : Tn - 1;
        for (int s = lo; s <= hi; ++s)
            ar += sc[s] * erv[((size_t)layer * (2 * WINn + 1) + (s - t + WINn)) * DKn + d];
        A[((size_t)(b * Cn + h * DKn + d)) * Tn + t] = (a + ar) * inv;
    }
}

// ---------------------------------------------------------------------------
// Residual add + LayerNorm over channel dim. X <- LN(X + Y) * g + b.
// One block: 32 t-positions, 256 threads (8 channel-groups x 32 lanes).
__global__ __launch_bounds__(256) void ln_k(
        float* __restrict__ X, const float* __restrict__ Y,
        const float* __restrict__ G, const float* __restrict__ Bt, int layer) {
    __shared__ float tile[Cn][32];
    __shared__ float r1[8][32];
    __shared__ float r2[8][32];
    const int tid = threadIdx.x;
    const int lane = tid & 31, w = tid >> 5;
    const int b = blockIdx.x >> 5;
    const int t = (blockIdx.x & 31) * 32 + lane;

    float s1 = 0.f, s2 = 0.f;
    for (int c = w; c < Cn; c += 8) {
        float v = X[((b * Cn + c) * Tn) + t] + Y[((b * Cn + c) * Tn) + t];
        tile[c][lane] = v;
        s1 += v;
        s2 += v * v;
    }
    r1[w][lane] = s1;
    r2[w][lane] = s2;
    __syncthreads();
    if (w == 0) {
        float a = 0.f, q = 0.f;
        for (int i = 0; i < 8; ++i) { a += r1[i][lane]; q += r2[i][lane]; }
        float m = a / Cn;
        float var = q / Cn - m * m;
        r1[0][lane] = m;
        r2[0][lane] = rsqrtf(var + 1e-5f);
    }
    __syncthreads();
    const float m = r1[0][lane], rs = r2[0][lane];
    for (int c = w; c < Cn; c += 8) {
        float g = G[layer * Cn + c], bb = Bt[layer * Cn + c];
        X[((b * Cn + c) * Tn) + t] = (tile[c][lane] - m) * rs * g + bb;
    }
}

// ---------------------------------------------------------------------------
extern "C" void kernel_launch(void* const* d_in, const int* in_sizes, int n_in,
                              void* d_out, int out_size, void* d_ws, size_t ws_size,
                              hipStream_t stream) {
    const float* x    = (const float*)d_in[0];
    const float* mask = (const float*)d_in[1];
    const float* Wq   = (const float*)d_in[2];
    const float* bq   = (const float*)d_in[3];
    const float* Wk   = (const float*)d_in[4];
    const float* bk   = (const float*)d_in[5];
    const float* Wv   = (const float*)d_in[6];
    const float* bv   = (const float*)d_in[7];
    const float* Wo   = (const float*)d_in[8];
    const float* bo   = (const float*)d_in[9];
    const float* erk  = (const float*)d_in[10];
    const float* erv  = (const float*)d_in[11];
    const float* ln1g = (const float*)d_in[12];
    const float* ln1b = (const float*)d_in[13];
    const float* w1   = (const float*)d_in[14];
    const float* b1   = (const float*)d_in[15];
    const float* w2   = (const float*)d_in[16];
    const float* b2   = (const float*)d_in[17];
    const float* ln2g = (const float*)d_in[18];
    const float* ln2b = (const float*)d_in[19];

    const size_t N = (size_t)Bn * Cn * Tn;  // 1572864
    float* X  = (float*)d_ws;
    float* Qb = X + N;
    float* Kb = X + 2 * N;
    float* Vb = X + 3 * N;
    float* Ab = X + 4 * N;
    float* Yb = Qb;          // Q is dead after attn; reuse for conv-o / FFN out
    float* Hb = X + 5 * N;   // B*FC*T floats (4N)

    cvt_in<<<(int)(N / 256), 256, 0, stream>>>(x, mask, X);

    for (int l = 0; l < Ln; ++l) {
        dim3 gp(Tn / 64, Cn / 64, Bn);
        conv_k<1><<<gp, 256, 0, stream>>>(X, Wq, bq, Qb, Cn, Cn, l, 0);
        conv_k<1><<<gp, 256, 0, stream>>>(X, Wk, bk, Kb, Cn, Cn, l, 0);
        conv_k<1><<<gp, 256, 0, stream>>>(X, Wv, bv, Vb, Cn, Cn, l, 0);
        attn_k<<<dim3(Tn, Hn, Bn), 128, 0, stream>>>(Qb, Kb, Vb, mask, erk, erv, Ab, l);
        conv_k<1><<<gp, 256, 0, stream>>>(Ab, Wo, bo, Yb, Cn, Cn, l, 0);
        ln_k<<<Bn * (Tn / 32), 256, 0, stream>>>(X, Yb, ln1g, ln1b, l);
        conv_k<3><<<dim3(Tn / 64, FCn / 64, Bn), 256, 0, stream>>>(X, w1, b1, Hb, Cn, FCn, l, 1);
        conv_k<3><<<dim3(Tn / 64, Cn / 64, Bn), 256, 0, stream>>>(Hb, w2, b2, Yb, FCn, Cn, l, 0);
        ln_k<<<Bn * (Tn / 32), 256, 0, stream>>>(X, Yb, ln2g, ln2b, l);
    }

    cvt_out<<<(int)(N / 256), 256, 0, stream>>>(X, mask, (float*)d_out);
}

// Round 3
// 5202.880 us; speedup vs baseline: 1.9548x; 1.9548x over previous
//
#include <hip/hip_runtime.h>
#include <hip/hip_bf16.h>

// Problem constants
constexpr int Bn  = 8;
constexpr int Cn  = 192;   // hidden channels
constexpr int Tn  = 1024;  // sequence length
constexpr int Hn  = 2;     // heads
constexpr int DKn = 96;    // head dim
constexpr int FCn = 768;   // filter channels
constexpr int Ln  = 6;     // layers
constexpr int WINn = 4;    // rel-attn window

// ---------------------------------------------------------------------------
// X = x * mask   (all fp32)
__global__ void cvt_in(const float* __restrict__ x, const float* __restrict__ mask,
                       float* __restrict__ X) {
    int i = blockIdx.x * 256 + threadIdx.x;           // i < B*C*T
    int t = i & (Tn - 1);
    int b = i / (Cn * Tn);
    X[i] = x[i] * mask[b * Tn + t];
}

// out = X * mask
__global__ void cvt_out(const float* __restrict__ X, const float* __restrict__ mask,
                        float* __restrict__ out) {
    int i = blockIdx.x * 256 + threadIdx.x;
    int t = i & (Tn - 1);
    int b = i / (Cn * Tn);
    out[i] = X[i] * mask[b * Tn + t];
}

// ---------------------------------------------------------------------------
// Generic conv1d (cross-correlation, 'same' padding (KS/2, KS/2)) / 1x1 GEMM.
template <int KS>
__global__ __launch_bounds__(256) void conv_k(
        const float* __restrict__ Xin, const float* __restrict__ Wg,
        const float* __restrict__ Bg, float* __restrict__ Yout,
        int CIN, int COUT, int layer, int relu) {
    constexpr int WD = 64 + KS - 1;       // staged x width
    constexpr int RW = 16 * KS + 1;       // ws row stride (+1 anti-bank-conflict)
    __shared__ float xs[16][WD];
    __shared__ float ws[64][RW];

    const int tid = threadIdx.x;
    const int b  = blockIdx.z;
    const int f0 = blockIdx.y * 64;
    const int t0 = blockIdx.x * 64;
    const int tx = tid & 15, ty = tid >> 4;

    const float* Wl = Wg + (size_t)layer * COUT * CIN * KS;

    float acc[4][4] = {};

    for (int c0 = 0; c0 < CIN; c0 += 16) {
        __syncthreads();
        for (int idx = tid; idx < 16 * WD; idx += 256) {
            int r = idx / WD, col = idx % WD;
            int gt = t0 + col - (KS / 2);
            float v = 0.f;
            if (gt >= 0 && gt < Tn) v = Xin[((b * CIN + c0 + r) * Tn) + gt];
            xs[r][col] = v;
        }
        for (int idx = tid; idx < 64 * 16 * KS; idx += 256) {
            int f = idx / (16 * KS), r = idx % (16 * KS);
            ws[f][r] = Wl[(size_t)(f0 + f) * CIN * KS + (size_t)c0 * KS + r];
        }
        __syncthreads();
#pragma unroll
        for (int cc = 0; cc < 16; ++cc) {
#pragma unroll
            for (int k = 0; k < KS; ++k) {
                float wv[4], xv[4];
#pragma unroll
                for (int i = 0; i < 4; ++i) wv[i] = ws[ty + 16 * i][cc * KS + k];
#pragma unroll
                for (int j = 0; j < 4; ++j) xv[j] = xs[cc][tx + 16 * j + k];
#pragma unroll
                for (int i = 0; i < 4; ++i)
#pragma unroll
                    for (int j = 0; j < 4; ++j) acc[i][j] += wv[i] * xv[j];
            }
        }
    }
#pragma unroll
    for (int i = 0; i < 4; ++i) {
        int f = f0 + ty + 16 * i;
        float bias = Bg[layer * COUT + f];
#pragma unroll
        for (int j = 0; j < 4; ++j) {
            float v = acc[i][j] + bias;
            if (relu) v = fmaxf(v, 0.f);
            Yout[((b * COUT + f) * Tn) + t0 + tx + 16 * j] = v;
        }
    }
}

// ---------------------------------------------------------------------------
// Tiled flash-style relative-position attention.
// Grid: (T/64, H, B); 256 threads. Q tile 64 rows; K/V chunks of 64 staged
// into one shared buffer (phased). Online softmax, rel-K via precomputed
// per-row 9-band table, rel-V on diagonal chunks.
__global__ __launch_bounds__(256, 2) void attn_tile(
        const float* __restrict__ Q, const float* __restrict__ K,
        const float* __restrict__ V, const float* __restrict__ mask,
        const float* __restrict__ erk, const float* __restrict__ erv,
        float* __restrict__ A, int layer) {
    __shared__ float qs[96][64];     // Q^T tile (scaled): [d][tq]
    __shared__ float kv[96][68];     // K chunk then V chunk: [d][s] (pad 68: b128 align + PV banks)
    __shared__ float pT[64][64];     // P transposed: [s][tq]
    __shared__ float rqk[64][9];     // per-row rel-K dot for delta -4..4
    __shared__ float rpart[64][17];  // row-stat partials (pad 17: conflict-free)
    __shared__ float mrow[64], lrow[64], arow[64], mt[64], ms[64];

    const int tid = threadIdx.x;
    const int t0 = blockIdx.x * 64;
    const int h = blockIdx.y, b = blockIdx.z;
    const size_t off = ((size_t)b * Cn + h * DKn) * Tn;
    const float scale = 0.10206207261596575f;  // 1/sqrt(96)

    // stage scaled Q^T (coalesced over t)
    for (int idx = tid; idx < 96 * 64; idx += 256) {
        int d = idx >> 6, tq = idx & 63;
        qs[d][tq] = Q[off + (size_t)d * Tn + t0 + tq] * scale;
    }
    if (tid < 64) { mt[tid] = mask[b * Tn + t0 + tid]; mrow[tid] = -3.0e38f; lrow[tid] = 0.f; }
    __syncthreads();

    // rqk[tq][dd] = sum_d qs[d][tq] * erk[l][dd][d]  (erk from global, L2-cached)
    const float* erkl = erk + (size_t)layer * 9 * DKn;
    for (int task = tid; task < 64 * 9; task += 256) {
        int tq = task & 63, dd = task >> 6;
        float a = 0.f;
        for (int d = 0; d < 96; ++d) a += qs[d][tq] * erkl[dd * 96 + d];
        rqk[tq][dd] = a;
    }

    const int i = tid & 15, j = tid >> 4;   // i: row group (4i..4i+3), j: col/d group
    float O[4][6] = {};                     // O[a][c]: row 4i+a, d = 6j+c

    const float* ervl = erv + (size_t)layer * 9 * DKn;

    for (int s0 = 0; s0 < Tn; s0 += 64) {
        __syncthreads();  // A: kv/pT/rpart free for reuse
        for (int idx = tid; idx < 96 * 64; idx += 256) {
            int d = idx >> 6, s = idx & 63;
            kv[d][s] = K[off + (size_t)d * Tn + s0 + s];
        }
        if (tid < 64) ms[tid] = mask[b * Tn + s0 + tid];
        __syncthreads();  // B

        // S = Q*K^T (4x4 register tile per thread)
        float S[4][4] = {};
        for (int d = 0; d < 96; ++d) {
            float4 qv = *(const float4*)&qs[d][4 * i];
            float4 kk = *(const float4*)&kv[d][4 * j];
            float qa[4] = {qv.x, qv.y, qv.z, qv.w};
            float ka[4] = {kk.x, kk.y, kk.z, kk.w};
#pragma unroll
            for (int a = 0; a < 4; ++a)
#pragma unroll
                for (int c = 0; c < 4; ++c) S[a][c] += qa[a] * ka[c];
        }
        // rel-K band + mask; per-row partial max
#pragma unroll
        for (int a = 0; a < 4; ++a) {
            const int tg = t0 + 4 * i + a;
            const float mtv = mt[4 * i + a];
            float pm = -3.0e38f;
#pragma unroll
            for (int c = 0; c < 4; ++c) {
                int sg = s0 + 4 * j + c;
                int dd = sg - tg + WINn;
                if (dd >= 0 && dd <= 2 * WINn) S[a][c] += rqk[4 * i + a][dd];
                if (mtv * ms[4 * j + c] == 0.f) S[a][c] = -1e4f;
                pm = fmaxf(pm, S[a][c]);
            }
            rpart[4 * i + a][j] = pm;
        }
        __syncthreads();  // C
        if (tid < 64) {
            float cm = -3.0e38f;
            for (int q = 0; q < 16; ++q) cm = fmaxf(cm, rpart[tid][q]);
            float mo = mrow[tid];
            float mn = fmaxf(mo, cm);
            arow[tid] = (mo <= -1.0e30f) ? 0.f : __expf(mo - mn);
            mrow[tid] = mn;
        }
        __syncthreads();  // D
        // P = exp(S - m), write transposed; partial sums; rescale O
#pragma unroll
        for (int a = 0; a < 4; ++a) {
            const float mn = mrow[4 * i + a];
            float ps = 0.f;
#pragma unroll
            for (int c = 0; c < 4; ++c) {
                float p = __expf(S[a][c] - mn);
                pT[4 * j + c][4 * i + a] = p;
                ps += p;
            }
            rpart[4 * i + a][j] = ps;
            const float al = arow[4 * i + a];
#pragma unroll
            for (int c = 0; c < 6; ++c) O[a][c] *= al;
        }
        __syncthreads();  // E
        if (tid < 64) {
            float cs = 0.f;
            for (int q = 0; q < 16; ++q) cs += rpart[tid][q];
            lrow[tid] = lrow[tid] * arow[tid] + cs;
        }
        // stage V chunk into kv (K fully consumed)
        for (int idx = tid; idx < 96 * 64; idx += 256) {
            int d = idx >> 6, s = idx & 63;
            kv[d][s] = V[off + (size_t)d * Tn + s0 + s];
        }
        __syncthreads();  // F

        // O += P^T-read * V
        for (int s = 0; s < 64; ++s) {
            float4 pv = *(const float4*)&pT[s][4 * i];
            float pa[4] = {pv.x, pv.y, pv.z, pv.w};
            float vv[6];
#pragma unroll
            for (int c = 0; c < 6; ++c) vv[c] = kv[6 * j + c][s];
#pragma unroll
            for (int a = 0; a < 4; ++a)
#pragma unroll
                for (int c = 0; c < 6; ++c) O[a][c] += pa[a] * vv[c];
        }
        // rel-V (diagonal chunks only)
        if (s0 + 63 >= t0 - WINn && s0 <= t0 + 63 + WINn) {
#pragma unroll
            for (int a = 0; a < 4; ++a) {
                const int tg = t0 + 4 * i + a;
                for (int dd = 0; dd <= 2 * WINn; ++dd) {
                    int sg = tg + dd - WINn;
                    if (sg >= s0 && sg < s0 + 64) {
                        float p = pT[sg - s0][4 * i + a];
#pragma unroll
                        for (int c = 0; c < 6; ++c) O[a][c] += p * ervl[dd * 96 + 6 * j + c];
                    }
                }
            }
        }
    }

    // epilogue: normalize and store (lrow final since last write precedes sync F)
#pragma unroll
    for (int a = 0; a < 4; ++a) {
        const float inv = 1.f / lrow[4 * i + a];
#pragma unroll
        for (int c = 0; c < 6; ++c)
            A[off + (size_t)(6 * j + c) * Tn + t0 + 4 * i + a] = O[a][c] * inv;
    }
}

// ---------------------------------------------------------------------------
// Residual add + LayerNorm over channel dim. X <- LN(X + Y) * g + b.
__global__ __launch_bounds__(256) void ln_k(
        float* __restrict__ X, const float* __restrict__ Y,
        const float* __restrict__ G, const float* __restrict__ Bt, int layer) {
    __shared__ float tile[Cn][32];
    __shared__ float r1[8][32];
    __shared__ float r2[8][32];
    const int tid = threadIdx.x;
    const int lane = tid & 31, w = tid >> 5;
    const int b = blockIdx.x >> 5;
    const int t = (blockIdx.x & 31) * 32 + lane;

    float s1 = 0.f, s2 = 0.f;
    for (int c = w; c < Cn; c += 8) {
        float v = X[((b * Cn + c) * Tn) + t] + Y[((b * Cn + c) * Tn) + t];
        tile[c][lane] = v;
        s1 += v;
        s2 += v * v;
    }
    r1[w][lane] = s1;
    r2[w][lane] = s2;
    __syncthreads();
    if (w == 0) {
        float a = 0.f, q = 0.f;
        for (int i = 0; i < 8; ++i) { a += r1[i][lane]; q += r2[i][lane]; }
        float m = a / Cn;
        float var = q / Cn - m * m;
        r1[0][lane] = m;
        r2[0][lane] = rsqrtf(var + 1e-5f);
    }
    __syncthreads();
    const float m = r1[0][lane], rs = r2[0][lane];
    for (int c = w; c < Cn; c += 8) {
        float g = G[layer * Cn + c], bb = Bt[layer * Cn + c];
        X[((b * Cn + c) * Tn) + t] = (tile[c][lane] - m) * rs * g + bb;
    }
}

// ---------------------------------------------------------------------------
extern "C" void kernel_launch(void* const* d_in, const int* in_sizes, int n_in,
                              void* d_out, int out_size, void* d_ws, size_t ws_size,
                              hipStream_t stream) {
    const float* x    = (const float*)d_in[0];
    const float* mask = (const float*)d_in[1];
    const float* Wq   = (const float*)d_in[2];
    const float* bq   = (const float*)d_in[3];
    const float* Wk   = (const float*)d_in[4];
    const float* bk   = (const float*)d_in[5];
    const float* Wv   = (const float*)d_in[6];
    const float* bv   = (const float*)d_in[7];
    const float* Wo   = (const float*)d_in[8];
    const float* bo   = (const float*)d_in[9];
    const float* erk  = (const float*)d_in[10];
    const float* erv  = (const float*)d_in[11];
    const float* ln1g = (const float*)d_in[12];
    const float* ln1b = (const float*)d_in[13];
    const float* w1   = (const float*)d_in[14];
    const float* b1   = (const float*)d_in[15];
    const float* w2   = (const float*)d_in[16];
    const float* b2   = (const float*)d_in[17];
    const float* ln2g = (const float*)d_in[18];
    const float* ln2b = (const float*)d_in[19];

    const size_t N = (size_t)Bn * Cn * Tn;  // 1572864
    float* X  = (float*)d_ws;
    float* Qb = X + N;
    float* Kb = X + 2 * N;
    float* Vb = X + 3 * N;
    float* Ab = X + 4 * N;
    float* Yb = Qb;          // Q is dead after attn; reuse for conv-o / FFN out
    float* Hb = X + 5 * N;   // B*FC*T floats (4N)

    cvt_in<<<(int)(N / 256), 256, 0, stream>>>(x, mask, X);

    for (int l = 0; l < Ln; ++l) {
        dim3 gp(Tn / 64, Cn / 64, Bn);
        conv_k<1><<<gp, 256, 0, stream>>>(X, Wq, bq, Qb, Cn, Cn, l, 0);
        conv_k<1><<<gp, 256, 0, stream>>>(X, Wk, bk, Kb, Cn, Cn, l, 0);
        conv_k<1><<<gp, 256, 0, stream>>>(X, Wv, bv, Vb, Cn, Cn, l, 0);
        attn_tile<<<dim3(Tn / 64, Hn, Bn), 256, 0, stream>>>(Qb, Kb, Vb, mask, erk, erv, Ab, l);
        conv_k<1><<<gp, 256, 0, stream>>>(Ab, Wo, bo, Yb, Cn, Cn, l, 0);
        ln_k<<<Bn * (Tn / 32), 256, 0, stream>>>(X, Yb, ln1g, ln1b, l);
        conv_k<3><<<dim3(Tn / 64, FCn / 64, Bn), 256, 0, stream>>>(X, w1, b1, Hb, Cn, FCn, l, 1);
        conv_k<3><<<dim3(Tn / 64, Cn / 64, Bn), 256, 0, stream>>>(Hb, w2, b2, Yb, FCn, Cn, l, 0);
        ln_k<<<Bn * (Tn / 32), 256, 0, stream>>>(X, Yb, ln2g, ln2b, l);
    }

    cvt_out<<<(int)(N / 256), 256, 0, stream>>>(X, mask, (float*)d_out);
}

// Round 4
// 2502.783 us; speedup vs baseline: 4.0636x; 2.0788x over previous
//
#include <hip/hip_runtime.h>
#include <hip/hip_bf16.h>

// Problem constants
constexpr int Bn  = 8;
constexpr int Cn  = 192;   // hidden channels
constexpr int Tn  = 1024;  // sequence length
constexpr int Hn  = 2;     // heads
constexpr int DKn = 96;    // head dim
constexpr int FCn = 768;   // filter channels
constexpr int Ln  = 6;     // layers
constexpr int WINn = 4;    // rel-attn window

typedef __hip_bfloat16 bf16;
typedef __attribute__((ext_vector_type(8))) short short8;
typedef __attribute__((ext_vector_type(4))) float f32x4;

// ---------------------------------------------------------------------------
// Weight transforms (once per call; ~6 MB of traffic total)
__global__ void cast_bf(const float* __restrict__ src, bf16* __restrict__ dst, int n) {
    int i = blockIdx.x * 256 + threadIdx.x;
    if (i < n) dst[i] = __float2bfloat16(src[i]);
}

// w [L][CO][CIN][3] -> [L][3][CO][CIN] bf16
__global__ void reorder_w(const float* __restrict__ src, bf16* __restrict__ dst,
                          int CO, int CIN) {
    int i = blockIdx.x * 256 + threadIdx.x;
    int n = Ln * 3 * CO * CIN;
    if (i >= n) return;
    int c = i % CIN;
    int f = (i / CIN) % CO;
    int ko = (i / (CIN * CO)) % 3;
    int l = i / (3 * CIN * CO);
    dst[i] = __float2bfloat16(src[(((size_t)(l * CO + f)) * CIN + c) * 3 + ko]);
}

// ---------------------------------------------------------------------------
// Input: X = x*mask (fp32, NCT) + XT = bf16 transposed [b][t][c]
__global__ __launch_bounds__(256) void cvt_in_k(
        const float* __restrict__ x, const float* __restrict__ mask,
        float* __restrict__ X, bf16* __restrict__ XT) {
    __shared__ float tile[Cn][33];
    const int tid = threadIdx.x, lane = tid & 31, w = tid >> 5;
    const int b = blockIdx.x >> 5;
    const int t0 = (blockIdx.x & 31) * 32;
    const float mk = mask[b * Tn + t0 + lane];
    for (int c = w; c < Cn; c += 8) {
        float v = x[((b * Cn + c) * Tn) + t0 + lane] * mk;
        X[((b * Cn + c) * Tn) + t0 + lane] = v;
        tile[c][lane] = v;
    }
    __syncthreads();
    for (int idx = tid; idx < 32 * Cn; idx += 256) {
        int tl = idx / Cn, c = idx % Cn;
        XT[((size_t)b * Tn + t0 + tl) * Cn + c] = __float2bfloat16(tile[c][tl]);
    }
}

// out = X * mask
__global__ void cvt_out(const float* __restrict__ X, const float* __restrict__ mask,
                        float* __restrict__ out) {
    int i = blockIdx.x * 256 + threadIdx.x;
    int t = i & (Tn - 1);
    int b = i / (Cn * Tn);
    out[i] = X[i] * mask[b * Tn + t];
}

// ---------------------------------------------------------------------------
// MFMA conv1d: Y[b,f,t] = sum_{c,ko} Xt[b][t+ko-PAD][c] * W[ko][f][c] + bias[f]
// A = X (m=t), B = W (n=f), K = c. 3 shifted GEMMs for KS=3.
// Grid (T/64, CO/64, B), 256 thr = 4 waves; wave w: f-range f0+16w, 4 m-blocks.
// MODE 0: fp32 NCT out (+bias, *mask if mask!=null)
// MODE 1: bf16 NCT out (+bias)                       [QKV]
// MODE 2: bf16 transposed [b][t][CO] out (relu(+bias))*mask  [FFN1]
template <int KS, int MODE>
__global__ __launch_bounds__(256) void conv_mfma(
        const bf16* __restrict__ Xt, const bf16* __restrict__ W,
        const float* __restrict__ bias, const float* __restrict__ mask,
        void* __restrict__ Yout, int CIN, int CO) {
    constexpr int PAD = KS / 2;
    const int tid = threadIdx.x;
    const int wv = tid >> 6, lane = tid & 63;
    const int m = lane & 15, kq = lane >> 4;
    const int b = blockIdx.z, t0 = blockIdx.x * 64;
    const int f = blockIdx.y * 64 + wv * 16 + m;  // B col and D col for this lane

    const bf16* xbase = Xt + (size_t)b * Tn * CIN + kq * 8;
    f32x4 acc[4] = {};

    for (int c0 = 0; c0 < CIN; c0 += 32) {
#pragma unroll
        for (int ko = 0; ko < KS; ++ko) {
            short8 bfr = *(const short8*)(W + ((size_t)(ko * CO + f)) * CIN + c0 + kq * 8);
#pragma unroll
            for (int mb = 0; mb < 4; ++mb) {
                int tr = t0 + mb * 16 + m + ko - PAD;
                short8 afr = {0, 0, 0, 0, 0, 0, 0, 0};
                if (PAD == 0 || (unsigned)tr < (unsigned)Tn)
                    afr = *(const short8*)(xbase + (size_t)tr * CIN + c0);
                acc[mb] = __builtin_amdgcn_mfma_f32_16x16x32_bf16(afr, bfr, acc[mb], 0, 0, 0);
            }
        }
    }
    // D layout: col = lane&15 (f), row = kq*4 + reg (t within 16-block)
    const float bs = bias[f];
    if (MODE == 0) {
        float* Y = (float*)Yout + ((size_t)b * CO + f) * Tn;
#pragma unroll
        for (int mb = 0; mb < 4; ++mb) {
            int t = t0 + mb * 16 + kq * 4;
            float4 o;
            o.x = acc[mb][0] + bs; o.y = acc[mb][1] + bs;
            o.z = acc[mb][2] + bs; o.w = acc[mb][3] + bs;
            if (mask) {
                o.x *= mask[b * Tn + t];     o.y *= mask[b * Tn + t + 1];
                o.z *= mask[b * Tn + t + 2]; o.w *= mask[b * Tn + t + 3];
            }
            *(float4*)(Y + t) = o;
        }
    } else if (MODE == 1) {
        bf16* Y = (bf16*)Yout + ((size_t)b * CO + f) * Tn;
#pragma unroll
        for (int mb = 0; mb < 4; ++mb) {
            int t = t0 + mb * 16 + kq * 4;
            bf16 tmp[4];
#pragma unroll
            for (int r = 0; r < 4; ++r) tmp[r] = __float2bfloat16(acc[mb][r] + bs);
            *(uint2*)(Y + t) = *(uint2*)tmp;
        }
    } else {
        bf16* Y = (bf16*)Yout;
#pragma unroll
        for (int mb = 0; mb < 4; ++mb) {
#pragma unroll
            for (int r = 0; r < 4; ++r) {
                int t = t0 + mb * 16 + kq * 4 + r;
                float v = fmaxf(acc[mb][r] + bs, 0.f) * mask[b * Tn + t];
                Y[((size_t)b * Tn + t) * CO + f] = __float2bfloat16(v);
            }
        }
    }
}

// ---------------------------------------------------------------------------
// Tiled flash-style relative-position attention (fp32 math, bf16 Q/K/V in).
// Writes bf16 transposed output AT[b][t][C] for the O-projection.
__global__ __launch_bounds__(256, 2) void attn_tile(
        const bf16* __restrict__ Q, const bf16* __restrict__ K,
        const bf16* __restrict__ V, const float* __restrict__ mask,
        const float* __restrict__ erk, const float* __restrict__ erv,
        bf16* __restrict__ AT, int layer) {
    __shared__ float qs[96][64];     // Q^T tile (scaled): [d][tq]
    __shared__ float kv[96][68];     // K chunk then V chunk: [d][s]
    __shared__ float pT[64][64];     // P transposed: [s][tq]
    __shared__ float rqk[64][9];     // per-row rel-K dot for delta -4..4
    __shared__ float rpart[64][17];  // row-stat partials
    __shared__ float mrow[64], lrow[64], arow[64], mt[64], ms[64];

    const int tid = threadIdx.x;
    const int t0 = blockIdx.x * 64;
    const int h = blockIdx.y, b = blockIdx.z;
    const size_t off = ((size_t)b * Cn + h * DKn) * Tn;
    const float scale = 0.10206207261596575f;  // 1/sqrt(96)

    for (int idx = tid; idx < 96 * 64; idx += 256) {
        int d = idx >> 6, tq = idx & 63;
        qs[d][tq] = __bfloat162float(Q[off + (size_t)d * Tn + t0 + tq]) * scale;
    }
    if (tid < 64) { mt[tid] = mask[b * Tn + t0 + tid]; mrow[tid] = -3.0e38f; lrow[tid] = 0.f; }
    __syncthreads();

    const float* erkl = erk + (size_t)layer * 9 * DKn;
    for (int task = tid; task < 64 * 9; task += 256) {
        int tq = task & 63, dd = task >> 6;
        float a = 0.f;
        for (int d = 0; d < 96; ++d) a += qs[d][tq] * erkl[dd * 96 + d];
        rqk[tq][dd] = a;
    }

    const int i = tid & 15, j = tid >> 4;
    float O[4][6] = {};
    const float* ervl = erv + (size_t)layer * 9 * DKn;

    for (int s0 = 0; s0 < Tn; s0 += 64) {
        __syncthreads();
        for (int idx = tid; idx < 96 * 64; idx += 256) {
            int d = idx >> 6, s = idx & 63;
            kv[d][s] = __bfloat162float(K[off + (size_t)d * Tn + s0 + s]);
        }
        if (tid < 64) ms[tid] = mask[b * Tn + s0 + tid];
        __syncthreads();

        float S[4][4] = {};
        for (int d = 0; d < 96; ++d) {
            float4 qv = *(const float4*)&qs[d][4 * i];
            float4 kk = *(const float4*)&kv[d][4 * j];
            float qa[4] = {qv.x, qv.y, qv.z, qv.w};
            float ka[4] = {kk.x, kk.y, kk.z, kk.w};
#pragma unroll
            for (int a = 0; a < 4; ++a)
#pragma unroll
                for (int c = 0; c < 4; ++c) S[a][c] += qa[a] * ka[c];
        }
#pragma unroll
        for (int a = 0; a < 4; ++a) {
            const int tg = t0 + 4 * i + a;
            const float mtv = mt[4 * i + a];
            float pm = -3.0e38f;
#pragma unroll
            for (int c = 0; c < 4; ++c) {
                int sg = s0 + 4 * j + c;
                int dd = sg - tg + WINn;
                if (dd >= 0 && dd <= 2 * WINn) S[a][c] += rqk[4 * i + a][dd];
                if (mtv * ms[4 * j + c] == 0.f) S[a][c] = -1e4f;
                pm = fmaxf(pm, S[a][c]);
            }
            rpart[4 * i + a][j] = pm;
        }
        __syncthreads();
        if (tid < 64) {
            float cm = -3.0e38f;
            for (int q = 0; q < 16; ++q) cm = fmaxf(cm, rpart[tid][q]);
            float mo = mrow[tid];
            float mn = fmaxf(mo, cm);
            arow[tid] = (mo <= -1.0e30f) ? 0.f : __expf(mo - mn);
            mrow[tid] = mn;
        }
        __syncthreads();
#pragma unroll
        for (int a = 0; a < 4; ++a) {
            const float mn = mrow[4 * i + a];
            float ps = 0.f;
#pragma unroll
            for (int c = 0; c < 4; ++c) {
                float p = __expf(S[a][c] - mn);
                pT[4 * j + c][4 * i + a] = p;
                ps += p;
            }
            rpart[4 * i + a][j] = ps;
            const float al = arow[4 * i + a];
#pragma unroll
            for (int c = 0; c < 6; ++c) O[a][c] *= al;
        }
        __syncthreads();
        if (tid < 64) {
            float cs = 0.f;
            for (int q = 0; q < 16; ++q) cs += rpart[tid][q];
            lrow[tid] = lrow[tid] * arow[tid] + cs;
        }
        for (int idx = tid; idx < 96 * 64; idx += 256) {
            int d = idx >> 6, s = idx & 63;
            kv[d][s] = __bfloat162float(V[off + (size_t)d * Tn + s0 + s]);
        }
        __syncthreads();

        for (int s = 0; s < 64; ++s) {
            float4 pv = *(const float4*)&pT[s][4 * i];
            float pa[4] = {pv.x, pv.y, pv.z, pv.w};
            float vv[6];
#pragma unroll
            for (int c = 0; c < 6; ++c) vv[c] = kv[6 * j + c][s];
#pragma unroll
            for (int a = 0; a < 4; ++a)
#pragma unroll
                for (int c = 0; c < 6; ++c) O[a][c] += pa[a] * vv[c];
        }
        if (s0 + 63 >= t0 - WINn && s0 <= t0 + 63 + WINn) {
#pragma unroll
            for (int a = 0; a < 4; ++a) {
                const int tg = t0 + 4 * i + a;
                for (int dd = 0; dd <= 2 * WINn; ++dd) {
                    int sg = tg + dd - WINn;
                    if (sg >= s0 && sg < s0 + 64) {
                        float p = pT[sg - s0][4 * i + a];
#pragma unroll
                        for (int c = 0; c < 6; ++c) O[a][c] += p * ervl[dd * 96 + 6 * j + c];
                    }
                }
            }
        }
    }

    // epilogue: normalize, write bf16 transposed [b][t][C]
#pragma unroll
    for (int a = 0; a < 4; ++a) {
        const float inv = 1.f / lrow[4 * i + a];
        bf16* dst = AT + ((size_t)b * Tn + t0 + 4 * i + a) * Cn + h * DKn + 6 * j;
#pragma unroll
        for (int c = 0; c < 6; ++c) dst[c] = __float2bfloat16(O[a][c] * inv);
    }
}

// ---------------------------------------------------------------------------
// Residual add + LayerNorm over channels. X <- LN(X+Y)*g+b (fp32) and
// XT <- bf16 transposed [b][t][C], optionally *mask.
__global__ __launch_bounds__(256) void ln_k(
        float* __restrict__ X, const float* __restrict__ Y,
        const float* __restrict__ G, const float* __restrict__ Bt,
        const float* __restrict__ mask, bf16* __restrict__ XT, int apply_mask) {
    __shared__ float tile[Cn][33];
    __shared__ float r1[8][32];
    __shared__ float r2[8][32];
    const int tid = threadIdx.x;
    const int lane = tid & 31, w = tid >> 5;
    const int b = blockIdx.x >> 5;
    const int t0 = (blockIdx.x & 31) * 32;
    const int t = t0 + lane;

    float s1 = 0.f, s2 = 0.f;
    for (int c = w; c < Cn; c += 8) {
        float v = X[((b * Cn + c) * Tn) + t] + Y[((b * Cn + c) * Tn) + t];
        tile[c][lane] = v;
        s1 += v;
        s2 += v * v;
    }
    r1[w][lane] = s1;
    r2[w][lane] = s2;
    __syncthreads();
    if (w == 0) {
        float a = 0.f, q = 0.f;
        for (int i = 0; i < 8; ++i) { a += r1[i][lane]; q += r2[i][lane]; }
        float m = a / Cn;
        float var = q / Cn - m * m;
        r1[0][lane] = m;
        r2[0][lane] = rsqrtf(var + 1e-5f);
    }
    __syncthreads();
    const float m = r1[0][lane], rs = r2[0][lane];
    for (int c = w; c < Cn; c += 8) {
        float y = (tile[c][lane] - m) * rs * G[c] + Bt[c];
        X[((b * Cn + c) * Tn) + t] = y;
        tile[c][lane] = y;
    }
    __syncthreads();
    for (int idx = tid; idx < 32 * Cn; idx += 256) {
        int tl = idx / Cn, c = idx % Cn;
        float v = tile[c][tl];
        if (apply_mask) v *= mask[b * Tn + t0 + tl];
        XT[((size_t)b * Tn + t0 + tl) * Cn + c] = __float2bfloat16(v);
    }
}

// ---------------------------------------------------------------------------
extern "C" void kernel_launch(void* const* d_in, const int* in_sizes, int n_in,
                              void* d_out, int out_size, void* d_ws, size_t ws_size,
                              hipStream_t stream) {
    const float* x    = (const float*)d_in[0];
    const float* mask = (const float*)d_in[1];
    const float* Wq   = (const float*)d_in[2];
    const float* bq   = (const float*)d_in[3];
    const float* Wk   = (const float*)d_in[4];
    const float* bk   = (const float*)d_in[5];
    const float* Wv   = (const float*)d_in[6];
    const float* bv   = (const float*)d_in[7];
    const float* Wo   = (const float*)d_in[8];
    const float* bo   = (const float*)d_in[9];
    const float* erk  = (const float*)d_in[10];
    const float* erv  = (const float*)d_in[11];
    const float* ln1g = (const float*)d_in[12];
    const float* ln1b = (const float*)d_in[13];
    const float* w1   = (const float*)d_in[14];
    const float* b1   = (const float*)d_in[15];
    const float* w2   = (const float*)d_in[16];
    const float* b2   = (const float*)d_in[17];
    const float* ln2g = (const float*)d_in[18];
    const float* ln2b = (const float*)d_in[19];

    const size_t N = (size_t)Bn * Cn * Tn;         // 1,572,864
    const int WC = Ln * Cn * Cn;                   // 221,184
    const size_t WF = (size_t)Ln * 3 * FCn * Cn;   // 2,654,208

    float* X  = (float*)d_ws;
    float* Yb = X + N;
    bf16* p16 = (bf16*)(Yb + N);
    bf16* XT  = p16; p16 += N;
    bf16* Qb  = p16; p16 += N;
    bf16* Kb  = p16; p16 += N;
    bf16* Vb  = p16; p16 += N;
    bf16* AT  = p16; p16 += N;
    bf16* HT  = p16; p16 += (size_t)Bn * Tn * FCn;
    bf16* Wqb = p16; p16 += WC;
    bf16* Wkb = p16; p16 += WC;
    bf16* Wvb = p16; p16 += WC;
    bf16* Wob = p16; p16 += WC;
    bf16* W1t = p16; p16 += WF;
    bf16* W2t = p16; p16 += WF;

    // one-time transforms
    cast_bf<<<(WC + 255) / 256, 256, 0, stream>>>(Wq, Wqb, WC);
    cast_bf<<<(WC + 255) / 256, 256, 0, stream>>>(Wk, Wkb, WC);
    cast_bf<<<(WC + 255) / 256, 256, 0, stream>>>(Wv, Wvb, WC);
    cast_bf<<<(WC + 255) / 256, 256, 0, stream>>>(Wo, Wob, WC);
    reorder_w<<<(int)((WF + 255) / 256), 256, 0, stream>>>(w1, W1t, FCn, Cn);
    reorder_w<<<(int)((WF + 255) / 256), 256, 0, stream>>>(w2, W2t, Cn, FCn);
    cvt_in_k<<<Bn * 32, 256, 0, stream>>>(x, mask, X, XT);

    for (int l = 0; l < Ln; ++l) {
        const size_t wc = (size_t)l * Cn * Cn;
        const dim3 g192(Tn / 64, Cn / 64, Bn);
        conv_mfma<1, 1><<<g192, 256, 0, stream>>>(XT, Wqb + wc, bq + l * Cn, nullptr, Qb, Cn, Cn);
        conv_mfma<1, 1><<<g192, 256, 0, stream>>>(XT, Wkb + wc, bk + l * Cn, nullptr, Kb, Cn, Cn);
        conv_mfma<1, 1><<<g192, 256, 0, stream>>>(XT, Wvb + wc, bv + l * Cn, nullptr, Vb, Cn, Cn);
        attn_tile<<<dim3(Tn / 64, Hn, Bn), 256, 0, stream>>>(Qb, Kb, Vb, mask, erk, erv, AT, l);
        conv_mfma<1, 0><<<g192, 256, 0, stream>>>(AT, Wob + wc, bo + l * Cn, nullptr, Yb, Cn, Cn);
        ln_k<<<Bn * 32, 256, 0, stream>>>(X, Yb, ln1g + l * Cn, ln1b + l * Cn, mask, XT, 1);
        conv_mfma<3, 2><<<dim3(Tn / 64, FCn / 64, Bn), 256, 0, stream>>>(
            XT, W1t + (size_t)l * 3 * FCn * Cn, b1 + l * FCn, mask, HT, Cn, FCn);
        conv_mfma<3, 0><<<g192, 256, 0, stream>>>(
            HT, W2t + (size_t)l * 3 * Cn * FCn, b2 + l * Cn, mask, Yb, FCn, Cn);
        ln_k<<<Bn * 32, 256, 0, stream>>>(X, Yb, ln2g + l * Cn, ln2b + l * Cn, mask, XT, 0);
    }

    cvt_out<<<(int)(N / 256), 256, 0, stream>>>(X, mask, (float*)d_out);
}

// Round 5
// 1915.305 us; speedup vs baseline: 5.3101x; 1.3067x over previous
//
#include <hip/hip_runtime.h>
#include <hip/hip_bf16.h>

// Problem constants
constexpr int Bn  = 8;
constexpr int Cn  = 192;   // hidden channels
constexpr int Tn  = 1024;  // sequence length
constexpr int Hn  = 2;     // heads
constexpr int DKn = 96;    // head dim
constexpr int FCn = 768;   // filter channels
constexpr int Ln  = 6;     // layers
constexpr int WINn = 4;    // rel-attn window

typedef __hip_bfloat16 bf16;
typedef __attribute__((ext_vector_type(8))) short short8;
typedef __attribute__((ext_vector_type(4))) float f32x4;

// ---------------------------------------------------------------------------
// Weight transforms (once per call)
__global__ void cast_bf(const float* __restrict__ src, bf16* __restrict__ dst, int n) {
    int i = blockIdx.x * 256 + threadIdx.x;
    if (i < n) dst[i] = __float2bfloat16(src[i]);
}

// w [L][CO][CIN][3] -> [L][3][CO][CIN] bf16
__global__ void reorder_w(const float* __restrict__ src, bf16* __restrict__ dst,
                          int CO, int CIN) {
    int i = blockIdx.x * 256 + threadIdx.x;
    int n = Ln * 3 * CO * CIN;
    if (i >= n) return;
    int c = i % CIN;
    int f = (i / CIN) % CO;
    int ko = (i / (CIN * CO)) % 3;
    int l = i / (3 * CIN * CO);
    dst[i] = __float2bfloat16(src[(((size_t)(l * CO + f)) * CIN + c) * 3 + ko]);
}

// ---------------------------------------------------------------------------
// Input: X = x*mask (fp32, NCT) + XT = bf16 transposed [b][t][c]
__global__ __launch_bounds__(256) void cvt_in_k(
        const float* __restrict__ x, const float* __restrict__ mask,
        float* __restrict__ X, bf16* __restrict__ XT) {
    __shared__ float tile[Cn][33];
    const int tid = threadIdx.x, lane = tid & 31, w = tid >> 5;
    const int b = blockIdx.x >> 5;
    const int t0 = (blockIdx.x & 31) * 32;
    const float mk = mask[b * Tn + t0 + lane];
    for (int c = w; c < Cn; c += 8) {
        float v = x[((b * Cn + c) * Tn) + t0 + lane] * mk;
        X[((b * Cn + c) * Tn) + t0 + lane] = v;
        tile[c][lane] = v;
    }
    __syncthreads();
    for (int idx = tid; idx < 32 * Cn; idx += 256) {
        int tl = idx / Cn, c = idx % Cn;
        XT[((size_t)b * Tn + t0 + tl) * Cn + c] = __float2bfloat16(tile[c][tl]);
    }
}

// out = X * mask
__global__ void cvt_out(const float* __restrict__ X, const float* __restrict__ mask,
                        float* __restrict__ out) {
    int i = blockIdx.x * 256 + threadIdx.x;
    int t = i & (Tn - 1);
    int b = i / (Cn * Tn);
    out[i] = X[i] * mask[b * Tn + t];
}

// ---------------------------------------------------------------------------
// MFMA conv1d: Y[b,f,t] = sum_{c,ko} Xt[b][t+ko-PAD][c] * W[ko][f][c] + bias[f]
// MODE 0: fp32 NCT out (+bias, *mask if mask!=null)
// MODE 1: bf16 NCT out (+bias)                         [V]
// MODE 2: bf16 transposed [b][t][CO] out relu(+bias)*mask  [FFN1]
// MODE 3: bf16 transposed [b][t][CO] out (+bias)*oscale    [Q,K]
template <int KS, int MODE>
__global__ __launch_bounds__(256) void conv_mfma(
        const bf16* __restrict__ Xt, const bf16* __restrict__ W,
        const float* __restrict__ bias, const float* __restrict__ mask,
        void* __restrict__ Yout, int CIN, int CO, float oscale) {
    constexpr int PAD = KS / 2;
    const int tid = threadIdx.x;
    const int wv = tid >> 6, lane = tid & 63;
    const int m = lane & 15, kq = lane >> 4;
    const int b = blockIdx.z, t0 = blockIdx.x * 64;
    const int f = blockIdx.y * 64 + wv * 16 + m;

    const bf16* xbase = Xt + (size_t)b * Tn * CIN + kq * 8;
    f32x4 acc[4] = {};

    for (int c0 = 0; c0 < CIN; c0 += 32) {
#pragma unroll
        for (int ko = 0; ko < KS; ++ko) {
            short8 bfr = *(const short8*)(W + ((size_t)(ko * CO + f)) * CIN + c0 + kq * 8);
#pragma unroll
            for (int mb = 0; mb < 4; ++mb) {
                int tr = t0 + mb * 16 + m + ko - PAD;
                short8 afr = {0, 0, 0, 0, 0, 0, 0, 0};
                if (PAD == 0 || (unsigned)tr < (unsigned)Tn)
                    afr = *(const short8*)(xbase + (size_t)tr * CIN + c0);
                acc[mb] = __builtin_amdgcn_mfma_f32_16x16x32_bf16(afr, bfr, acc[mb], 0, 0, 0);
            }
        }
    }
    const float bs = bias[f];
    if (MODE == 0) {
        float* Y = (float*)Yout + ((size_t)b * CO + f) * Tn;
#pragma unroll
        for (int mb = 0; mb < 4; ++mb) {
            int t = t0 + mb * 16 + kq * 4;
            float4 o;
            o.x = acc[mb][0] + bs; o.y = acc[mb][1] + bs;
            o.z = acc[mb][2] + bs; o.w = acc[mb][3] + bs;
            if (mask) {
                o.x *= mask[b * Tn + t];     o.y *= mask[b * Tn + t + 1];
                o.z *= mask[b * Tn + t + 2]; o.w *= mask[b * Tn + t + 3];
            }
            *(float4*)(Y + t) = o;
        }
    } else if (MODE == 1) {
        bf16* Y = (bf16*)Yout + ((size_t)b * CO + f) * Tn;
#pragma unroll
        for (int mb = 0; mb < 4; ++mb) {
            int t = t0 + mb * 16 + kq * 4;
            bf16 tmp[4];
#pragma unroll
            for (int r = 0; r < 4; ++r) tmp[r] = __float2bfloat16(acc[mb][r] + bs);
            *(uint2*)(Y + t) = *(uint2*)tmp;
        }
    } else if (MODE == 2) {
        bf16* Y = (bf16*)Yout;
#pragma unroll
        for (int mb = 0; mb < 4; ++mb) {
#pragma unroll
            for (int r = 0; r < 4; ++r) {
                int t = t0 + mb * 16 + kq * 4 + r;
                float v = fmaxf(acc[mb][r] + bs, 0.f) * mask[b * Tn + t];
                Y[((size_t)b * Tn + t) * CO + f] = __float2bfloat16(v);
            }
        }
    } else {
        bf16* Y = (bf16*)Yout;
#pragma unroll
        for (int mb = 0; mb < 4; ++mb) {
#pragma unroll
            for (int r = 0; r < 4; ++r) {
                int t = t0 + mb * 16 + kq * 4 + r;
                Y[((size_t)b * Tn + t) * CO + f] = __float2bfloat16((acc[mb][r] + bs) * oscale);
            }
        }
    }
}

// ---------------------------------------------------------------------------
// MFMA flash attention. QT/KT: bf16 [b][t][C] (Q pre-scaled by 1/sqrt(dk)),
// V: bf16 NCT. Out: AT bf16 [b][t][C]. Grid (T/64, H, B), 256 thr = 4 waves;
// wave w owns q-rows [t0+16w, t0+16w+16). Main loop is barrier-free
// (per-wave LDS only).
__global__ __launch_bounds__(256) void attn_mfma(
        const bf16* __restrict__ QT, const bf16* __restrict__ KT,
        const bf16* __restrict__ V, const float* __restrict__ mask,
        const float* __restrict__ erk, const float* __restrict__ erv,
        bf16* __restrict__ AT, int layer) {
    __shared__ float rqk[64][12];     // rel-K band table: [tq-t0][delta+4]
    __shared__ bf16 pT[4][16][72];    // per-wave P: [m][s] (pad 72: 2-way max)

    const int tid = threadIdx.x, wv = tid >> 6, lane = tid & 63;
    const int col = lane & 15, quad = lane >> 4;
    const int t0 = blockIdx.x * 64, h = blockIdx.y, b = blockIdx.z;
    const int hd = h * DKn;
    const int t0w = t0 + wv * 16;

    // rel-K band: rqk[tq][dd] = sum_d QTs[t0+tq][hd+d] * erk[l][dd][d]
    const float* erkl = erk + (size_t)layer * 9 * DKn;
    for (int task = tid; task < 64 * 9; task += 256) {
        int tq = task & 63, dd = task >> 6;
        const bf16* qrow = QT + ((size_t)b * Tn + t0 + tq) * Cn + hd;
        float a = 0.f;
        for (int d = 0; d < DKn; ++d) a += __bfloat162float(qrow[d]) * erkl[dd * DKn + d];
        rqk[tq][dd] = a;
    }
    __syncthreads();

    // Q A-frags (persist whole kernel): A[m=col][k=kd*32+quad*8+j]
    short8 aq[3];
    {
        const bf16* qrow = QT + ((size_t)b * Tn + t0w + col) * Cn + hd + quad * 8;
#pragma unroll
        for (int kd = 0; kd < 3; ++kd) aq[kd] = *(const short8*)(qrow + kd * 32);
    }
    float mtv[4];
#pragma unroll
    for (int r = 0; r < 4; ++r) mtv[r] = mask[b * Tn + t0w + quad * 4 + r];

    float mold[4] = {-3.0e38f, -3.0e38f, -3.0e38f, -3.0e38f};
    float lrow[4] = {};
    f32x4 O[6] = {};
    const float* ervl = erv + (size_t)layer * 9 * DKn;

    for (int s0 = 0; s0 < Tn; s0 += 64) {
        // K B-frags: B[n=col][k=kd*32+quad*8+j] from KT rows s0+16nb+col
        short8 bk[4][3];
#pragma unroll
        for (int nb = 0; nb < 4; ++nb) {
            const bf16* krow = KT + ((size_t)b * Tn + s0 + 16 * nb + col) * Cn + hd + quad * 8;
#pragma unroll
            for (int kd = 0; kd < 3; ++kd) bk[nb][kd] = *(const short8*)(krow + kd * 32);
        }
        // V B-frags: B[n=col (d)][k=kk*32+quad*8+j (s)] from V NCT
        short8 bv[6][2];
#pragma unroll
        for (int nd = 0; nd < 6; ++nd) {
            const bf16* vrow = V + ((size_t)(b * Cn + hd + 16 * nd + col)) * Tn + s0 + quad * 8;
#pragma unroll
            for (int kk = 0; kk < 2; ++kk) bv[nd][kk] = *(const short8*)(vrow + kk * 32);
        }

        // S = Q K^T
        f32x4 S[4] = {};
#pragma unroll
        for (int nb = 0; nb < 4; ++nb)
#pragma unroll
            for (int kd = 0; kd < 3; ++kd)
                S[nb] = __builtin_amdgcn_mfma_f32_16x16x32_bf16(aq[kd], bk[nb][kd], S[nb], 0, 0, 0);

        // rel-K band + mask  (C layout: row=quad*4+r, col within tile = lane&15)
#pragma unroll
        for (int nb = 0; nb < 4; ++nb) {
            const int sg = s0 + 16 * nb + col;
            const float msv = mask[b * Tn + sg];
#pragma unroll
            for (int r = 0; r < 4; ++r) {
                const int tq = t0w + quad * 4 + r;
                float v = S[nb][r];
                int dd = sg - tq + WINn;
                if (dd >= 0 && dd <= 2 * WINn) v += rqk[tq - t0][dd];
                if (msv * mtv[r] == 0.f) v = -1e4f;
                S[nb][r] = v;
            }
        }

        // online softmax (wave-local: 16-lane shuffle reductions)
        float mnew[4], alpha[4], psum[4];
#pragma unroll
        for (int r = 0; r < 4; ++r) {
            float mc = fmaxf(fmaxf(S[0][r], S[1][r]), fmaxf(S[2][r], S[3][r]));
#pragma unroll
            for (int mk2 = 1; mk2 < 16; mk2 <<= 1) mc = fmaxf(mc, __shfl_xor(mc, mk2));
            mnew[r] = fmaxf(mold[r], mc);
            alpha[r] = (mold[r] <= -1.0e30f) ? 0.f : __expf(mold[r] - mnew[r]);
            mold[r] = mnew[r];
            psum[r] = 0.f;
        }
#pragma unroll
        for (int nb = 0; nb < 4; ++nb)
#pragma unroll
            for (int r = 0; r < 4; ++r) {
                bf16 pb = __float2bfloat16(__expf(S[nb][r] - mnew[r]));
                pT[wv][quad * 4 + r][16 * nb + col] = pb;
                psum[r] += __bfloat162float(pb);
            }
#pragma unroll
        for (int r = 0; r < 4; ++r) {
#pragma unroll
            for (int mk2 = 1; mk2 < 16; mk2 <<= 1) psum[r] += __shfl_xor(psum[r], mk2);
            lrow[r] = lrow[r] * alpha[r] + psum[r];
#pragma unroll
            for (int nd = 0; nd < 6; ++nd) O[nd][r] *= alpha[r];
        }

        // P A-frags from per-wave LDS (wave-synchronous; compiler waits lgkmcnt)
        short8 aP[2];
#pragma unroll
        for (int kk = 0; kk < 2; ++kk)
            aP[kk] = *(const short8*)&pT[wv][col][kk * 32 + quad * 8];
#pragma unroll
        for (int nd = 0; nd < 6; ++nd)
#pragma unroll
            for (int kk = 0; kk < 2; ++kk)
                O[nd] = __builtin_amdgcn_mfma_f32_16x16x32_bf16(aP[kk], bv[nd][kk], O[nd], 0, 0, 0);

        // rel-V on diagonal chunks
        if (s0 <= t0w + 15 + WINn && s0 + 63 >= t0w - WINn) {
#pragma unroll
            for (int r = 0; r < 4; ++r) {
                const int tq = t0w + quad * 4 + r;
                for (int dd = 0; dd <= 2 * WINn; ++dd) {
                    int sg = tq + dd - WINn;
                    if (sg >= s0 && sg < s0 + 64) {
                        float p = __bfloat162float(pT[wv][quad * 4 + r][sg - s0]);
#pragma unroll
                        for (int nd = 0; nd < 6; ++nd)
                            O[nd][r] += p * ervl[dd * DKn + 16 * nd + col];
                    }
                }
            }
        }
    }

    // epilogue: normalize, write AT [b][t][C]
#pragma unroll
    for (int r = 0; r < 4; ++r) {
        const float inv = 1.f / lrow[r];
        bf16* dst = AT + ((size_t)b * Tn + t0w + quad * 4 + r) * Cn + hd + col;
#pragma unroll
        for (int nd = 0; nd < 6; ++nd)
            dst[16 * nd] = __float2bfloat16(O[nd][r] * inv);
    }
}

// ---------------------------------------------------------------------------
// Residual add + LayerNorm over channels. X <- LN(X+Y)*g+b (fp32) and
// XT <- bf16 transposed [b][t][C], optionally *mask.
__global__ __launch_bounds__(256) void ln_k(
        float* __restrict__ X, const float* __restrict__ Y,
        const float* __restrict__ G, const float* __restrict__ Bt,
        const float* __restrict__ mask, bf16* __restrict__ XT, int apply_mask) {
    __shared__ float tile[Cn][33];
    __shared__ float r1[8][32];
    __shared__ float r2[8][32];
    const int tid = threadIdx.x;
    const int lane = tid & 31, w = tid >> 5;
    const int b = blockIdx.x >> 5;
    const int t0 = (blockIdx.x & 31) * 32;
    const int t = t0 + lane;

    float s1 = 0.f, s2 = 0.f;
    for (int c = w; c < Cn; c += 8) {
        float v = X[((b * Cn + c) * Tn) + t] + Y[((b * Cn + c) * Tn) + t];
        tile[c][lane] = v;
        s1 += v;
        s2 += v * v;
    }
    r1[w][lane] = s1;
    r2[w][lane] = s2;
    __syncthreads();
    if (w == 0) {
        float a = 0.f, q = 0.f;
        for (int i = 0; i < 8; ++i) { a += r1[i][lane]; q += r2[i][lane]; }
        float m = a / Cn;
        float var = q / Cn - m * m;
        r1[0][lane] = m;
        r2[0][lane] = rsqrtf(var + 1e-5f);
    }
    __syncthreads();
    const float m = r1[0][lane], rs = r2[0][lane];
    for (int c = w; c < Cn; c += 8) {
        float y = (tile[c][lane] - m) * rs * G[c] + Bt[c];
        X[((b * Cn + c) * Tn) + t] = y;
        tile[c][lane] = y;
    }
    __syncthreads();
    for (int idx = tid; idx < 32 * Cn; idx += 256) {
        int tl = idx / Cn, c = idx % Cn;
        float v = tile[c][tl];
        if (apply_mask) v *= mask[b * Tn + t0 + tl];
        XT[((size_t)b * Tn + t0 + tl) * Cn + c] = __float2bfloat16(v);
    }
}

// ---------------------------------------------------------------------------
extern "C" void kernel_launch(void* const* d_in, const int* in_sizes, int n_in,
                              void* d_out, int out_size, void* d_ws, size_t ws_size,
                              hipStream_t stream) {
    const float* x    = (const float*)d_in[0];
    const float* mask = (const float*)d_in[1];
    const float* Wq   = (const float*)d_in[2];
    const float* bq   = (const float*)d_in[3];
    const float* Wk   = (const float*)d_in[4];
    const float* bk   = (const float*)d_in[5];
    const float* Wv   = (const float*)d_in[6];
    const float* bv   = (const float*)d_in[7];
    const float* Wo   = (const float*)d_in[8];
    const float* bo   = (const float*)d_in[9];
    const float* erk  = (const float*)d_in[10];
    const float* erv  = (const float*)d_in[11];
    const float* ln1g = (const float*)d_in[12];
    const float* ln1b = (const float*)d_in[13];
    const float* w1   = (const float*)d_in[14];
    const float* b1   = (const float*)d_in[15];
    const float* w2   = (const float*)d_in[16];
    const float* b2   = (const float*)d_in[17];
    const float* ln2g = (const float*)d_in[18];
    const float* ln2b = (const float*)d_in[19];

    const size_t N = (size_t)Bn * Cn * Tn;         // 1,572,864
    const int WC = Ln * Cn * Cn;                   // 221,184
    const size_t WF = (size_t)Ln * 3 * FCn * Cn;   // 2,654,208

    float* X  = (float*)d_ws;
    float* Yb = X + N;
    bf16* p16 = (bf16*)(Yb + N);
    bf16* XT  = p16; p16 += N;
    bf16* QTb = p16; p16 += N;
    bf16* KTb = p16; p16 += N;
    bf16* Vb  = p16; p16 += N;
    bf16* AT  = p16; p16 += N;
    bf16* HT  = p16; p16 += (size_t)Bn * Tn * FCn;
    bf16* Wqb = p16; p16 += WC;
    bf16* Wkb = p16; p16 += WC;
    bf16* Wvb = p16; p16 += WC;
    bf16* Wob = p16; p16 += WC;
    bf16* W1t = p16; p16 += WF;
    bf16* W2t = p16; p16 += WF;

    const float qscale = 0.10206207261596575f;  // 1/sqrt(96)

    // one-time transforms
    cast_bf<<<(WC + 255) / 256, 256, 0, stream>>>(Wq, Wqb, WC);
    cast_bf<<<(WC + 255) / 256, 256, 0, stream>>>(Wk, Wkb, WC);
    cast_bf<<<(WC + 255) / 256, 256, 0, stream>>>(Wv, Wvb, WC);
    cast_bf<<<(WC + 255) / 256, 256, 0, stream>>>(Wo, Wob, WC);
    reorder_w<<<(int)((WF + 255) / 256), 256, 0, stream>>>(w1, W1t, FCn, Cn);
    reorder_w<<<(int)((WF + 255) / 256), 256, 0, stream>>>(w2, W2t, Cn, FCn);
    cvt_in_k<<<Bn * 32, 256, 0, stream>>>(x, mask, X, XT);

    for (int l = 0; l < Ln; ++l) {
        const size_t wc = (size_t)l * Cn * Cn;
        const dim3 g192(Tn / 64, Cn / 64, Bn);
        conv_mfma<1, 3><<<g192, 256, 0, stream>>>(XT, Wqb + wc, bq + l * Cn, nullptr, QTb, Cn, Cn, qscale);
        conv_mfma<1, 3><<<g192, 256, 0, stream>>>(XT, Wkb + wc, bk + l * Cn, nullptr, KTb, Cn, Cn, 1.f);
        conv_mfma<1, 1><<<g192, 256, 0, stream>>>(XT, Wvb + wc, bv + l * Cn, nullptr, Vb, Cn, Cn, 1.f);
        attn_mfma<<<dim3(Tn / 64, Hn, Bn), 256, 0, stream>>>(QTb, KTb, Vb, mask, erk, erv, AT, l);
        conv_mfma<1, 0><<<g192, 256, 0, stream>>>(AT, Wob + wc, bo + l * Cn, nullptr, Yb, Cn, Cn, 1.f);
        ln_k<<<Bn * 32, 256, 0, stream>>>(X, Yb, ln1g + l * Cn, ln1b + l * Cn, mask, XT, 1);
        conv_mfma<3, 2><<<dim3(Tn / 64, FCn / 64, Bn), 256, 0, stream>>>(
            XT, W1t + (size_t)l * 3 * FCn * Cn, b1 + l * FCn, mask, HT, Cn, FCn, 1.f);
        conv_mfma<3, 0><<<g192, 256, 0, stream>>>(
            HT, W2t + (size_t)l * 3 * Cn * FCn, b2 + l * Cn, mask, Yb, FCn, Cn, 1.f);
        ln_k<<<Bn * 32, 256, 0, stream>>>(X, Yb, ln2g + l * Cn, ln2b + l * Cn, mask, XT, 0);
    }

    cvt_out<<<(int)(N / 256), 256, 0, stream>>>(X, mask, (float*)d_out);
}

// Round 6
// 1779.007 us; speedup vs baseline: 5.7169x; 1.0766x over previous
//
#include <hip/hip_runtime.h>
#include <hip/hip_bf16.h>

// Problem constants
constexpr int Bn  = 8;
constexpr int Cn  = 192;   // hidden channels
constexpr int Tn  = 1024;  // sequence length
constexpr int Hn  = 2;     // heads
constexpr int DKn = 96;    // head dim
constexpr int FCn = 768;   // filter channels
constexpr int Ln  = 6;     // layers
constexpr int WINn = 4;    // rel-attn window
constexpr int QKS = 384;   // QK transposed row stride (Q|K concat)

typedef __hip_bfloat16 bf16;
typedef __attribute__((ext_vector_type(8))) short short8;
typedef __attribute__((ext_vector_type(4))) float f32x4;

// ---------------------------------------------------------------------------
// One-time transforms
__global__ void cast_bf(const float* __restrict__ src, bf16* __restrict__ dst, int n) {
    int i = blockIdx.x * 256 + threadIdx.x;
    if (i < n) dst[i] = __float2bfloat16(src[i]);
}

// w [L][CO][CIN][3] -> [L][3][CO][CIN] bf16
__global__ void reorder_w(const float* __restrict__ src, bf16* __restrict__ dst,
                          int CO, int CIN) {
    int i = blockIdx.x * 256 + threadIdx.x;
    int n = Ln * 3 * CO * CIN;
    if (i >= n) return;
    int c = i % CIN;
    int f = (i / CIN) % CO;
    int ko = (i / (CIN * CO)) % 3;
    int l = i / (3 * CIN * CO);
    dst[i] = __float2bfloat16(src[(((size_t)(l * CO + f)) * CIN + c) * 3 + ko]);
}

// Build fused QKV weight [L][576][C] bf16 (qscale folded into Q) + bias fp32
__global__ void qkv_prep(const float* __restrict__ Wq, const float* __restrict__ Wk,
                         const float* __restrict__ Wv, const float* __restrict__ bq,
                         const float* __restrict__ bk, const float* __restrict__ bv,
                         bf16* __restrict__ Wout, float* __restrict__ bout, float qscale) {
    int i = blockIdx.x * 256 + threadIdx.x;
    const int nW = Ln * 576 * Cn;
    if (i < nW) {
        int c = i % Cn, f = (i / Cn) % 576, l = i / (Cn * 576);
        float v;
        if (f < 192)      v = Wq[((size_t)l * Cn + f) * Cn + c] * qscale;
        else if (f < 384) v = Wk[((size_t)l * Cn + f - 192) * Cn + c];
        else              v = Wv[((size_t)l * Cn + f - 384) * Cn + c];
        Wout[i] = __float2bfloat16(v);
    } else if (i < nW + Ln * 576) {
        int j = i - nW, f = j % 576, l = j / 576;
        float v;
        if (f < 192)      v = bq[l * Cn + f] * qscale;
        else if (f < 384) v = bk[l * Cn + f - 192];
        else              v = bv[l * Cn + f - 384];
        bout[j] = v;
    }
}

// ---------------------------------------------------------------------------
// Input: X = x*mask (fp32, NCT) + XT = bf16 transposed [b][t][c]
__global__ __launch_bounds__(256) void cvt_in_k(
        const float* __restrict__ x, const float* __restrict__ mask,
        float* __restrict__ X, bf16* __restrict__ XT) {
    __shared__ float tile[Cn][33];
    const int tid = threadIdx.x, lane = tid & 31, w = tid >> 5;
    const int b = blockIdx.x >> 5;
    const int t0 = (blockIdx.x & 31) * 32;
    const float mk = mask[b * Tn + t0 + lane];
    for (int c = w; c < Cn; c += 8) {
        float v = x[((b * Cn + c) * Tn) + t0 + lane] * mk;
        X[((b * Cn + c) * Tn) + t0 + lane] = v;
        tile[c][lane] = v;
    }
    __syncthreads();
    for (int idx = tid; idx < 32 * Cn; idx += 256) {
        int tl = idx / Cn, c = idx % Cn;
        XT[((size_t)b * Tn + t0 + tl) * Cn + c] = __float2bfloat16(tile[c][tl]);
    }
}

// out = X * mask
__global__ void cvt_out(const float* __restrict__ X, const float* __restrict__ mask,
                        float* __restrict__ out) {
    int i = blockIdx.x * 256 + threadIdx.x;
    int t = i & (Tn - 1);
    int b = i / (Cn * Tn);
    out[i] = X[i] * mask[b * Tn + t];
}

// ---------------------------------------------------------------------------
// MFMA conv1d, software-pipelined (double-buffered fragments).
// Y[b,f,t] = sum_{c,ko} Xt[b][t+ko-PAD][c] * W[ko][f][c] + bias[f]
// TT: t-tile (32 or 64). Grid (T/TT, CO/64, B); 4 waves; wave wv: f0+16wv.
// MODE 0: fp32 NCT out (+bias, *mask if mask!=null)
// MODE 2: bf16 transposed [b][t][CO] out relu(+bias)*mask   [FFN1]
// MODE 4: QKV split: f<384 -> bf16 T (stride QKS) into Y0; else bf16 NCT Y1
template <int KS, int TT, int MODE>
__global__ __launch_bounds__(256) void conv_mfma(
        const bf16* __restrict__ Xt, const bf16* __restrict__ W,
        const float* __restrict__ bias, const float* __restrict__ mask,
        void* __restrict__ Y0, void* __restrict__ Y1, int CIN, int CO) {
    constexpr int PAD = KS / 2;
    constexpr int NMB = TT / 16;
    const int tid = threadIdx.x;
    const int wv = tid >> 6, lane = tid & 63;
    const int m = lane & 15, kq = lane >> 4;
    const int b = blockIdx.z, t0 = blockIdx.x * TT;
    const int f = blockIdx.y * 64 + wv * 16 + m;

    const bf16* xbase = Xt + (size_t)b * Tn * CIN + kq * 8;
    const bf16* wrow = W + (size_t)f * CIN + kq * 8;
    const size_t wko = (size_t)CO * CIN;

    f32x4 acc[NMB] = {};
    short8 A0[NMB][KS], B0[KS], A1[NMB][KS], B1[KS];

    auto LOAD = [&](int c0, short8 (&A)[NMB][KS], short8 (&Bf)[KS]) {
#pragma unroll
        for (int ko = 0; ko < KS; ++ko) {
            Bf[ko] = *(const short8*)(wrow + ko * wko + c0);
#pragma unroll
            for (int mb = 0; mb < NMB; ++mb) {
                int tr = t0 + mb * 16 + m + ko - PAD;
                short8 a = {0, 0, 0, 0, 0, 0, 0, 0};
                if (PAD == 0 || (unsigned)tr < (unsigned)Tn)
                    a = *(const short8*)(xbase + (size_t)tr * CIN + c0);
                A[mb][ko] = a;
            }
        }
    };
    auto STEP = [&](short8 (&A)[NMB][KS], short8 (&Bf)[KS]) {
#pragma unroll
        for (int ko = 0; ko < KS; ++ko)
#pragma unroll
            for (int mb = 0; mb < NMB; ++mb)
                acc[mb] = __builtin_amdgcn_mfma_f32_16x16x32_bf16(A[mb][ko], Bf[ko], acc[mb], 0, 0, 0);
    };

    LOAD(0, A0, B0);
    for (int c0 = 0; c0 < CIN; c0 += 64) {   // CIN % 64 == 0
        if (c0 + 32 < CIN) LOAD(c0 + 32, A1, B1);
        STEP(A0, B0);
        if (c0 + 64 < CIN) LOAD(c0 + 64, A0, B0);
        STEP(A1, B1);
    }

    const float bs = bias[f];
    if (MODE == 0) {
        float* Y = (float*)Y0 + ((size_t)b * CO + f) * Tn;
#pragma unroll
        for (int mb = 0; mb < NMB; ++mb) {
            int t = t0 + mb * 16 + kq * 4;
            float4 o;
            o.x = acc[mb][0] + bs; o.y = acc[mb][1] + bs;
            o.z = acc[mb][2] + bs; o.w = acc[mb][3] + bs;
            if (mask) {
                o.x *= mask[b * Tn + t];     o.y *= mask[b * Tn + t + 1];
                o.z *= mask[b * Tn + t + 2]; o.w *= mask[b * Tn + t + 3];
            }
            *(float4*)(Y + t) = o;
        }
    } else if (MODE == 2) {
        bf16* Y = (bf16*)Y0;
#pragma unroll
        for (int mb = 0; mb < NMB; ++mb)
#pragma unroll
            for (int r = 0; r < 4; ++r) {
                int t = t0 + mb * 16 + kq * 4 + r;
                float v = fmaxf(acc[mb][r] + bs, 0.f) * mask[b * Tn + t];
                Y[((size_t)b * Tn + t) * CO + f] = __float2bfloat16(v);
            }
    } else {  // MODE 4
        if (blockIdx.y < 6) {          // Q|K -> transposed, stride QKS
            bf16* Y = (bf16*)Y0;
#pragma unroll
            for (int mb = 0; mb < NMB; ++mb)
#pragma unroll
                for (int r = 0; r < 4; ++r) {
                    int t = t0 + mb * 16 + kq * 4 + r;
                    Y[((size_t)b * Tn + t) * QKS + f] = __float2bfloat16(acc[mb][r] + bs);
                }
        } else {                        // V -> bf16 NCT
            bf16* Y = (bf16*)Y1 + ((size_t)b * Cn + f - 384) * Tn;
#pragma unroll
            for (int mb = 0; mb < NMB; ++mb) {
                int t = t0 + mb * 16 + kq * 4;
                bf16 tmp[4];
#pragma unroll
                for (int r = 0; r < 4; ++r) tmp[r] = __float2bfloat16(acc[mb][r] + bs);
                *(uint2*)(Y + t) = *(uint2*)tmp;
            }
        }
    }
}

// ---------------------------------------------------------------------------
// MFMA flash attention. QK: bf16 [b][t][384] (Q cols 0..191 pre-scaled, K cols
// 192..383), V: bf16 NCT. Out: AT bf16 [b][t][C]. Grid (T/64, H, B); 4 waves;
// wave wv owns q-rows [t0+16wv, +16). Main loop barrier-free (per-wave LDS).
__global__ __launch_bounds__(256) void attn_mfma(
        const bf16* __restrict__ QK, const bf16* __restrict__ V,
        const float* __restrict__ mask, const float* __restrict__ erk,
        const float* __restrict__ erv, bf16* __restrict__ AT, int layer) {
    __shared__ float rqk[64][12];     // rel-K band table: [tq-t0][delta+4]
    __shared__ bf16 pT[4][16][72];    // per-wave P: [m][s]

    const int tid = threadIdx.x, wv = tid >> 6, lane = tid & 63;
    const int col = lane & 15, quad = lane >> 4;
    const int t0 = blockIdx.x * 64, h = blockIdx.y, b = blockIdx.z;
    const int hd = h * DKn;
    const int t0w = t0 + wv * 16;

    const float* erkl = erk + (size_t)layer * 9 * DKn;
    for (int task = tid; task < 64 * 9; task += 256) {
        int tq = task & 63, dd = task >> 6;
        const bf16* qrow = QK + ((size_t)b * Tn + t0 + tq) * QKS + hd;
        float a = 0.f;
        for (int d = 0; d < DKn; ++d) a += __bfloat162float(qrow[d]) * erkl[dd * DKn + d];
        rqk[tq][dd] = a;
    }
    __syncthreads();

    short8 aq[3];
    {
        const bf16* qrow = QK + ((size_t)b * Tn + t0w + col) * QKS + hd + quad * 8;
#pragma unroll
        for (int kd = 0; kd < 3; ++kd) aq[kd] = *(const short8*)(qrow + kd * 32);
    }
    float mtv[4];
#pragma unroll
    for (int r = 0; r < 4; ++r) mtv[r] = mask[b * Tn + t0w + quad * 4 + r];

    float mold[4] = {-3.0e38f, -3.0e38f, -3.0e38f, -3.0e38f};
    float lrow[4] = {};
    f32x4 O[6] = {};
    const float* ervl = erv + (size_t)layer * 9 * DKn;

    for (int s0 = 0; s0 < Tn; s0 += 64) {
        short8 bk[4][3];
#pragma unroll
        for (int nb = 0; nb < 4; ++nb) {
            const bf16* krow = QK + ((size_t)b * Tn + s0 + 16 * nb + col) * QKS + 192 + hd + quad * 8;
#pragma unroll
            for (int kd = 0; kd < 3; ++kd) bk[nb][kd] = *(const short8*)(krow + kd * 32);
        }
        short8 bv[6][2];
#pragma unroll
        for (int nd = 0; nd < 6; ++nd) {
            const bf16* vrow = V + ((size_t)(b * Cn + hd + 16 * nd + col)) * Tn + s0 + quad * 8;
#pragma unroll
            for (int kk = 0; kk < 2; ++kk) bv[nd][kk] = *(const short8*)(vrow + kk * 32);
        }

        f32x4 S[4] = {};
#pragma unroll
        for (int nb = 0; nb < 4; ++nb)
#pragma unroll
            for (int kd = 0; kd < 3; ++kd)
                S[nb] = __builtin_amdgcn_mfma_f32_16x16x32_bf16(aq[kd], bk[nb][kd], S[nb], 0, 0, 0);

#pragma unroll
        for (int nb = 0; nb < 4; ++nb) {
            const int sg = s0 + 16 * nb + col;
            const float msv = mask[b * Tn + sg];
#pragma unroll
            for (int r = 0; r < 4; ++r) {
                const int tq = t0w + quad * 4 + r;
                float v = S[nb][r];
                int dd = sg - tq + WINn;
                if (dd >= 0 && dd <= 2 * WINn) v += rqk[tq - t0][dd];
                if (msv * mtv[r] == 0.f) v = -1e4f;
                S[nb][r] = v;
            }
        }

        float mnew[4], alpha[4], psum[4];
#pragma unroll
        for (int r = 0; r < 4; ++r) {
            float mc = fmaxf(fmaxf(S[0][r], S[1][r]), fmaxf(S[2][r], S[3][r]));
#pragma unroll
            for (int mk2 = 1; mk2 < 16; mk2 <<= 1) mc = fmaxf(mc, __shfl_xor(mc, mk2));
            mnew[r] = fmaxf(mold[r], mc);
            alpha[r] = (mold[r] <= -1.0e30f) ? 0.f : __expf(mold[r] - mnew[r]);
            mold[r] = mnew[r];
            psum[r] = 0.f;
        }
#pragma unroll
        for (int nb = 0; nb < 4; ++nb)
#pragma unroll
            for (int r = 0; r < 4; ++r) {
                bf16 pb = __float2bfloat16(__expf(S[nb][r] - mnew[r]));
                pT[wv][quad * 4 + r][16 * nb + col] = pb;
                psum[r] += __bfloat162float(pb);
            }
#pragma unroll
        for (int r = 0; r < 4; ++r) {
#pragma unroll
            for (int mk2 = 1; mk2 < 16; mk2 <<= 1) psum[r] += __shfl_xor(psum[r], mk2);
            lrow[r] = lrow[r] * alpha[r] + psum[r];
#pragma unroll
            for (int nd = 0; nd < 6; ++nd) O[nd][r] *= alpha[r];
        }

        short8 aP[2];
#pragma unroll
        for (int kk = 0; kk < 2; ++kk)
            aP[kk] = *(const short8*)&pT[wv][col][kk * 32 + quad * 8];
#pragma unroll
        for (int nd = 0; nd < 6; ++nd)
#pragma unroll
            for (int kk = 0; kk < 2; ++kk)
                O[nd] = __builtin_amdgcn_mfma_f32_16x16x32_bf16(aP[kk], bv[nd][kk], O[nd], 0, 0, 0);

        if (s0 <= t0w + 15 + WINn && s0 + 63 >= t0w - WINn) {
#pragma unroll
            for (int r = 0; r < 4; ++r) {
                const int tq = t0w + quad * 4 + r;
                for (int dd = 0; dd <= 2 * WINn; ++dd) {
                    int sg = tq + dd - WINn;
                    if (sg >= s0 && sg < s0 + 64) {
                        float p = __bfloat162float(pT[wv][quad * 4 + r][sg - s0]);
#pragma unroll
                        for (int nd = 0; nd < 6; ++nd)
                            O[nd][r] += p * ervl[dd * DKn + 16 * nd + col];
                    }
                }
            }
        }
    }

#pragma unroll
    for (int r = 0; r < 4; ++r) {
        const float inv = 1.f / lrow[r];
        bf16* dst = AT + ((size_t)b * Tn + t0w + quad * 4 + r) * Cn + hd + col;
#pragma unroll
        for (int nd = 0; nd < 6; ++nd)
            dst[16 * nd] = __float2bfloat16(O[nd][r] * inv);
    }
}

// ---------------------------------------------------------------------------
// Residual add + LayerNorm over channels. X <- LN(X+Y)*g+b (fp32) and
// XT <- bf16 transposed [b][t][C], optionally *mask.
__global__ __launch_bounds__(256) void ln_k(
        float* __restrict__ X, const float* __restrict__ Y,
        const float* __restrict__ G, const float* __restrict__ Bt,
        const float* __restrict__ mask, bf16* __restrict__ XT, int apply_mask) {
    __shared__ float tile[Cn][33];
    __shared__ float r1[8][32];
    __shared__ float r2[8][32];
    const int tid = threadIdx.x;
    const int lane = tid & 31, w = tid >> 5;
    const int b = blockIdx.x >> 5;
    const int t0 = (blockIdx.x & 31) * 32;
    const int t = t0 + lane;

    float s1 = 0.f, s2 = 0.f;
    for (int c = w; c < Cn; c += 8) {
        float v = X[((b * Cn + c) * Tn) + t] + Y[((b * Cn + c) * Tn) + t];
        tile[c][lane] = v;
        s1 += v;
        s2 += v * v;
    }
    r1[w][lane] = s1;
    r2[w][lane] = s2;
    __syncthreads();
    if (w == 0) {
        float a = 0.f, q = 0.f;
        for (int i = 0; i < 8; ++i) { a += r1[i][lane]; q += r2[i][lane]; }
        float m = a / Cn;
        float var = q / Cn - m * m;
        r1[0][lane] = m;
        r2[0][lane] = rsqrtf(var + 1e-5f);
    }
    __syncthreads();
    const float m = r1[0][lane], rs = r2[0][lane];
    for (int c = w; c < Cn; c += 8) {
        float y = (tile[c][lane] - m) * rs * G[c] + Bt[c];
        X[((b * Cn + c) * Tn) + t] = y;
        tile[c][lane] = y;
    }
    __syncthreads();
    for (int idx = tid; idx < 32 * Cn; idx += 256) {
        int tl = idx / Cn, c = idx % Cn;
        float v = tile[c][tl];
        if (apply_mask) v *= mask[b * Tn + t0 + tl];
        XT[((size_t)b * Tn + t0 + tl) * Cn + c] = __float2bfloat16(v);
    }
}

// ---------------------------------------------------------------------------
extern "C" void kernel_launch(void* const* d_in, const int* in_sizes, int n_in,
                              void* d_out, int out_size, void* d_ws, size_t ws_size,
                              hipStream_t stream) {
    const float* x    = (const float*)d_in[0];
    const float* mask = (const float*)d_in[1];
    const float* Wq   = (const float*)d_in[2];
    const float* bq   = (const float*)d_in[3];
    const float* Wk   = (const float*)d_in[4];
    const float* bk   = (const float*)d_in[5];
    const float* Wv   = (const float*)d_in[6];
    const float* bv   = (const float*)d_in[7];
    const float* Wo   = (const float*)d_in[8];
    const float* bo   = (const float*)d_in[9];
    const float* erk  = (const float*)d_in[10];
    const float* erv  = (const float*)d_in[11];
    const float* ln1g = (const float*)d_in[12];
    const float* ln1b = (const float*)d_in[13];
    const float* w1   = (const float*)d_in[14];
    const float* b1   = (const float*)d_in[15];
    const float* w2   = (const float*)d_in[16];
    const float* b2   = (const float*)d_in[17];
    const float* ln2g = (const float*)d_in[18];
    const float* ln2b = (const float*)d_in[19];

    const size_t N = (size_t)Bn * Cn * Tn;         // 1,572,864
    const int WC = Ln * Cn * Cn;                   // 221,184
    const size_t WF = (size_t)Ln * 3 * FCn * Cn;   // 2,654,208
    const size_t WQKV = (size_t)Ln * 576 * Cn;     // 663,552

    float* X    = (float*)d_ws;
    float* Yb   = X + N;
    float* bqkv = Yb + N;                          // L*576 floats
    bf16* p16 = (bf16*)(bqkv + Ln * 576);
    bf16* XT   = p16; p16 += N;
    bf16* QKT  = p16; p16 += (size_t)Bn * Tn * QKS;
    bf16* Vb   = p16; p16 += N;
    bf16* AT   = p16; p16 += N;
    bf16* HT   = p16; p16 += (size_t)Bn * Tn * FCn;
    bf16* Wqkv = p16; p16 += WQKV;
    bf16* Wob  = p16; p16 += WC;
    bf16* W1t  = p16; p16 += WF;
    bf16* W2t  = p16; p16 += WF;

    const float qscale = 0.10206207261596575f;  // 1/sqrt(96)

    // one-time transforms
    qkv_prep<<<(int)((WQKV + Ln * 576 + 255) / 256), 256, 0, stream>>>(
        Wq, Wk, Wv, bq, bk, bv, Wqkv, bqkv, qscale);
    cast_bf<<<(WC + 255) / 256, 256, 0, stream>>>(Wo, Wob, WC);
    reorder_w<<<(int)((WF + 255) / 256), 256, 0, stream>>>(w1, W1t, FCn, Cn);
    reorder_w<<<(int)((WF + 255) / 256), 256, 0, stream>>>(w2, W2t, Cn, FCn);
    cvt_in_k<<<Bn * 32, 256, 0, stream>>>(x, mask, X, XT);

    for (int l = 0; l < Ln; ++l) {
        conv_mfma<1, 64, 4><<<dim3(Tn / 64, 9, Bn), 256, 0, stream>>>(
            XT, Wqkv + (size_t)l * 576 * Cn, bqkv + l * 576, nullptr, QKT, Vb, Cn, 576);
        attn_mfma<<<dim3(Tn / 64, Hn, Bn), 256, 0, stream>>>(QKT, Vb, mask, erk, erv, AT, l);
        conv_mfma<1, 32, 0><<<dim3(Tn / 32, 3, Bn), 256, 0, stream>>>(
            AT, Wob + (size_t)l * Cn * Cn, bo + l * Cn, nullptr, Yb, nullptr, Cn, Cn);
        ln_k<<<Bn * 32, 256, 0, stream>>>(X, Yb, ln1g + l * Cn, ln1b + l * Cn, mask, XT, 1);
        conv_mfma<3, 64, 2><<<dim3(Tn / 64, FCn / 64, Bn), 256, 0, stream>>>(
            XT, W1t + (size_t)l * 3 * FCn * Cn, b1 + l * FCn, mask, HT, nullptr, Cn, FCn);
        conv_mfma<3, 32, 0><<<dim3(Tn / 32, 3, Bn), 256, 0, stream>>>(
            HT, W2t + (size_t)l * 3 * Cn * FCn, b2 + l * Cn, mask, Yb, nullptr, FCn, Cn);
        ln_k<<<Bn * 32, 256, 0, stream>>>(X, Yb, ln2g + l * Cn, ln2b + l * Cn, mask, XT, 0);
    }

    cvt_out<<<(int)(N / 256), 256, 0, stream>>>(X, mask, (float*)d_out);
}